// Round 16
// baseline (16840.678 us; speedup 1.0000x reference)
//
#include <hip/hip_runtime.h>
#include <math.h>

// NDDE forward-Euler DDE solve, D=768, N=8192 steps.
// x_{j+1} = x_j + dt * tanh(Wx x_j + Wy x_{j-10} + b),  dt = tau/10.
// Output: trajectory [D][N+1] fp32, out[i*(N+1)+k] = x_k[i].
//
// NUMERICS ARE FROZEN (passes at absmax 16.0 / thr 16.4): fp64-exact dots
// rounded per-dot to fp32; fp32 adds for z; correctly-rounded fp32 tanh via
// fp64; fp32 state update mul-then-add; per-row 32-lane x 24-col ownership,
// FMA order and shuffle reduction tree IDENTICAL to rounds 5/11/13.
//
// Round 16 = r13 (96x256, best at 14.25 ms) + dual-stream counted-vmcnt
// sweep. r11->r13 proved detect-phase quantization (sweep period, taken as
// a max over 96 WGs) is the dominant residual; dual-stream halves the
// sampling period. The losing stream stays IN FLIGHT across the barrier:
// the barrier is lgkmcnt(0)+s_barrier only (T4 pattern), never vmcnt(0), so
// no drain lands on the critical path; streams settle at the next step's
// sweep start (free, >2000cy later). Stream regs (12 VGPRs) are loop-carried
// and kept alive so the allocator can never hand them to other values while
// a load is in flight.
//
// Encoded lessons: no fences (r3), no RMWs (r7), no extra detect hop (r9),
// no setprio on spinners (r6), no replication (r8), no pure-poller waves
// (r6/r12), no non-coherent speculative reads (r14), 96x256 > 64x384 (r15),
// VGPR must fit weights (r4/r10), LDS stride 33 (r13).

#define DD 768
#define NSTEPS 8192
#define NWG 96
#define NT 256
#define ROWS_PER_WG 8
#define COLS_PER_LANE 24
#define RING 16
#define LSTRIDE 33
#define LSLOT (COLS_PER_LANE * LSTRIDE)   // 792 words per history slot

#define RING_OFF 0   // RING * DD * 8B packs in d_ws

typedef __attribute__((ext_vector_type(4))) unsigned int u32x4;
typedef __attribute__((ext_vector_type(2))) unsigned int u32x2;

__device__ __forceinline__ unsigned long long ld_tag(const unsigned long long* p) {
    return __hip_atomic_load(p, __ATOMIC_RELAXED, __HIP_MEMORY_SCOPE_AGENT);
}

// Issue one stream (2 requests, 3 packs) WITHOUT waiting.
__device__ __forceinline__ void issue3(const unsigned long long* p4,
                                       const unsigned long long* p2,
                                       u32x4* q, u32x2* s) {
    asm volatile("global_load_dwordx4 %0, %2, off sc0 sc1\n\t"
                 "global_load_dwordx2 %1, %3, off sc0 sc1"
                 : "=&v"(*q), "=&v"(*s)
                 : "v"(p4), "v"(p2)
                 : "memory");
}
// Wait until only the other stream (2 loads) is outstanding. The "+v" ties
// make the subsequent tag checks depend on THIS wait (un-hoistable).
__device__ __forceinline__ void wait_keep2(u32x4* q, u32x2* s) {
    asm volatile("s_waitcnt vmcnt(2)" : "+v"(*q), "+v"(*s) :: "memory");
}
__device__ __forceinline__ void wait_all0() {
    asm volatile("s_waitcnt vmcnt(0)" ::: "memory");
}

__global__ __launch_bounds__(NT, 1)
void ndde_kernel(const float* __restrict__ x0,
                 const float* __restrict__ tau,
                 const float* __restrict__ Wx,
                 const float* __restrict__ Wy,
                 const float* __restrict__ b,
                 float* __restrict__ out,
                 unsigned long long* __restrict__ ring)
{
    // Padded transposed f32 LDS history (r13): column i at
    // hist[slot*LSLOT + (i%24)*33 + i/24]. Dot-read bank=(k+c)%32 —
    // conflict-free; broadcast writes ~6-way.
    __shared__ float hist[RING * LSLOT];          // 50.7 KB

    const int tid = threadIdx.x;
    const int g   = blockIdx.x;
    const int r   = tid >> 5;            // local row 0..7
    const int c   = tid & 31;            // lane-within-row 0..31
    const int row = g * ROWS_PER_WG + r;
    const int cb  = c * COLS_PER_LANE;

    const float dtf = tau[0] / 10.0f;

    // ---- stage weights as f32 (cvt to f64 at use, exact) ----
    float wxf[COLS_PER_LANE], wyf[COLS_PER_LANE];
    {
        const float* px = Wx + row * DD + cb;
        const float* py = Wy + row * DD + cb;
        #pragma unroll
        for (int i = 0; i < COLS_PER_LANE / 4; ++i) {
            float4 a = *(const float4*)(px + 4 * i);
            wxf[4*i+0] = a.x; wxf[4*i+1] = a.y; wxf[4*i+2] = a.z; wxf[4*i+3] = a.w;
            float4 d2 = *(const float4*)(py + 4 * i);
            wyf[4*i+0] = d2.x; wyf[4*i+1] = d2.y; wyf[4*i+2] = d2.z; wyf[4*i+3] = d2.w;
        }
    }
    #pragma unroll
    for (int i = 0; i < COLS_PER_LANE; ++i) {
        asm volatile("" : "+v"(wxf[i]));
        asm volatile("" : "+v"(wyf[i]));
    }

    const float brow = b[row];
    float xrow = x0[row];                // lane c==0 carries x_j[row]
    if (c == 0) out[row * (NSTEPS + 1) + 0] = xrow;

    // Persistent dual-stream registers (loop-carried; never reused by the
    // allocator while a load may be in flight).
    u32x4 qa = {0,0,0,0}, qb = {0,0,0,0};
    u32x2 sa = {0,0},     sb = {0,0};

    for (int j = 0; j < NSTEPS; ++j) {
        // ---- delayed half: y = x_{j-10} from LDS history (frozen math) ----
        double dy0 = 0.0, dy1 = 0.0;
        if (j <= 10) {
            const float* ys = x0 + cb;
            #pragma unroll
            for (int i = 0; i < COLS_PER_LANE / 4; ++i) {
                float4 v = *(const float4*)(ys + 4 * i);
                dy0 = fma((double)wyf[4*i+0], (double)v.x, dy0);
                dy1 = fma((double)wyf[4*i+1], (double)v.y, dy1);
                dy0 = fma((double)wyf[4*i+2], (double)v.z, dy0);
                dy1 = fma((double)wyf[4*i+3], (double)v.w, dy1);
            }
        } else {
            const float* hs = hist + ((j - 10) & (RING - 1)) * LSLOT;
            #pragma unroll
            for (int k = 0; k < COLS_PER_LANE; k += 4) {
                float v0 = hs[(k+0)*LSTRIDE + c];
                float v1 = hs[(k+1)*LSTRIDE + c];
                float v2 = hs[(k+2)*LSTRIDE + c];
                float v3 = hs[(k+3)*LSTRIDE + c];
                dy0 = fma((double)wyf[k+0], (double)v0, dy0);
                dy1 = fma((double)wyf[k+1], (double)v1, dy1);
                dy0 = fma((double)wyf[k+2], (double)v2, dy0);
                dy1 = fma((double)wyf[k+3], (double)v3, dy1);
            }
        }
        double doty = dy0 + dy1;
        #pragma unroll
        for (int off = 1; off < 32; off <<= 1)
            doty += __shfl_xor(doty, off);

        // ---- dual-stream sweep: sampling period ~RT/2; losing stream stays
        // in flight across the (lgkm-only) barrier ----
        if (j >= 1) {
            // keep stream regs alive; settle last step's in-flight (free now)
            asm volatile("" : "+v"(qa), "+v"(sa), "+v"(qb), "+v"(sb));
            wait_all0();

            const unsigned tgt = (unsigned)j;
            const unsigned long long* base = ring + (j & (RING - 1)) * DD;
            const unsigned long long* p4 = base + 2 * tid;    // packs 2t,2t+1
            const unsigned long long* p2 = base + 512 + tid;  // pack 512+t
            unsigned v0, v1, v2;

            issue3(p4, p2, &qa, &sa);                 // A in flight (2)
            int tries = 0;
            for (;;) {
                if (tries < 1024) {
                    issue3(p4, p2, &qb, &sb);         // B in flight (4)
                    wait_keep2(&qa, &sa);             // A landed
                    if (__all((qa.y == tgt) & (qa.w == tgt) & (sa.y == tgt))) {
                        v0 = qa.x; v1 = qa.z; v2 = sa.x;  // B stays in flight
                        break;
                    }
                    issue3(p4, p2, &qa, &sa);         // A reissue (4)
                    wait_keep2(&qb, &sb);             // B landed
                    if (__all((qb.y == tgt) & (qb.w == tgt) & (sb.y == tgt))) {
                        v0 = qb.x; v1 = qb.z; v2 = sb.x;  // A stays in flight
                        break;
                    }
                    tries += 2;
                } else {
                    // proven fallback (no-hang): settle, serialized 8B polls
                    wait_all0();
                    unsigned long long q0 = ld_tag(p4 + 0);
                    unsigned long long q1 = ld_tag(p4 + 1);
                    unsigned long long q2 = ld_tag(p2);
                    v0 = (unsigned)q0; v1 = (unsigned)q1; v2 = (unsigned)q2;
                    if (__all(((unsigned)(q0 >> 32) == tgt) &
                              ((unsigned)(q1 >> 32) == tgt) &
                              ((unsigned)(q2 >> 32) == tgt)))
                        break;
                }
            }

            float* hsw = hist + (j & (RING - 1)) * LSLOT;
            const int iA = 2 * tid, iB = 2 * tid + 1, iC = 512 + tid;
            hsw[(iA % 24) * LSTRIDE + (iA / 24)] = __uint_as_float(v0);
            hsw[(iB % 24) * LSTRIDE + (iB / 24)] = __uint_as_float(v1);
            hsw[(iC % 24) * LSTRIDE + (iC / 24)] = __uint_as_float(v2);

            // lgkm-only barrier: LDS writes ordered, VMEM stays in flight
            asm volatile("s_waitcnt lgkmcnt(0)" ::: "memory");
            __builtin_amdgcn_s_barrier();
        }

        // ---- live half: Wx · x_j from LDS (frozen math) ----
        double dx0 = 0.0, dx1 = 0.0;
        if (j == 0) {
            const float* xs = x0 + cb;
            #pragma unroll
            for (int i = 0; i < COLS_PER_LANE / 4; ++i) {
                float4 v = *(const float4*)(xs + 4 * i);
                dx0 = fma((double)wxf[4*i+0], (double)v.x, dx0);
                dx1 = fma((double)wxf[4*i+1], (double)v.y, dx1);
                dx0 = fma((double)wxf[4*i+2], (double)v.z, dx0);
                dx1 = fma((double)wxf[4*i+3], (double)v.w, dx1);
            }
        } else {
            const float* hs = hist + (j & (RING - 1)) * LSLOT;
            #pragma unroll
            for (int k = 0; k < COLS_PER_LANE; k += 4) {
                float v0 = hs[(k+0)*LSTRIDE + c];
                float v1 = hs[(k+1)*LSTRIDE + c];
                float v2 = hs[(k+2)*LSTRIDE + c];
                float v3 = hs[(k+3)*LSTRIDE + c];
                dx0 = fma((double)wxf[k+0], (double)v0, dx0);
                dx1 = fma((double)wxf[k+1], (double)v1, dx1);
                dx0 = fma((double)wxf[k+2], (double)v2, dx0);
                dx1 = fma((double)wxf[k+3], (double)v3, dx1);
            }
        }
        double dotx = dx0 + dx1;
        #pragma unroll
        for (int off = 1; off < 32; off <<= 1)
            dotx += __shfl_xor(dotx, off);

        if (c == 0) {
            // z = (dot1_f32 + dot2_f32) + b, all fp32 adds (frozen)
            float z = __fadd_rn(__fadd_rn((float)dotx, (float)doty), brow);
            float th;
            float az = fabsf(z);
            if (az < 9.3f) th = (float)tanh((double)z);  // correctly-rounded
            else           th = (z > 0.0f) ? 1.0f : -1.0f;
            // x_next = x + dt*F, fp32 mul then fp32 add (frozen)
            xrow = __fadd_rn(xrow, __fmul_rn(dtf, th));

            // publish: (value|tag) in one relaxed agent-scope 8B store
            unsigned long long pack =
                ((unsigned long long)(unsigned)(j + 1) << 32) |
                (unsigned long long)__float_as_uint(xrow);
            __hip_atomic_store(&ring[((j + 1) & (RING - 1)) * DD + row], pack,
                               __ATOMIC_RELAXED, __HIP_MEMORY_SCOPE_AGENT);

            // trajectory write — off the critical path
            out[row * (NSTEPS + 1) + (j + 1)] = xrow;
        }
    }

    // settle any in-flight stream loads before wave exit
    asm volatile("" : "+v"(qa), "+v"(sa), "+v"(qb), "+v"(sb));
    wait_all0();
}

extern "C" void kernel_launch(void* const* d_in, const int* in_sizes, int n_in,
                              void* d_out, int out_size, void* d_ws, size_t ws_size,
                              hipStream_t stream) {
    (void)in_sizes; (void)n_in; (void)out_size; (void)ws_size;

    const float* x0  = (const float*)d_in[0];
    const float* tau = (const float*)d_in[1];
    const float* Wx  = (const float*)d_in[2];
    const float* Wy  = (const float*)d_in[3];
    const float* b   = (const float*)d_in[4];
    float* out = (float*)d_out;

    unsigned long long* ring = (unsigned long long*)((char*)d_ws + RING_OFF);

    // No memset needed: strict tag==j matching rejects 0xAA poison and stale
    // replay tags (slot j%16 is freshly rewritten long before step j needs it).
    ndde_kernel<<<NWG, NT, 0, stream>>>(x0, tau, Wx, Wy, b, out, ring);
}

// Round 17
// 16369.966 us; speedup vs baseline: 1.0288x; 1.0288x over previous
//
#include <hip/hip_runtime.h>
#include <math.h>

// NDDE forward-Euler DDE solve, D=768, N=8192 steps.
// x_{j+1} = x_j + dt * tanh(Wx x_j + Wy x_{j-10} + b),  dt = tau/10.
// Output: trajectory [D][N+1] fp32, out[i*(N+1)+k] = x_k[i].
//
// NUMERICS ARE FROZEN (passes at absmax 16.0 / thr 16.4): fp64-exact dots
// rounded per-dot to fp32; fp32 adds for z; correctly-rounded fp32 tanh via
// fp64; fp32 state update mul-then-add; per-row 32-lane x 24-col ownership,
// FMA order and shuffle reduction tree IDENTICAL to rounds 5/11/13. Only
// row->WG bookkeeping (row = 16g + r) differs.
//
// Round 17 topology test: 48 WGs x 512 thr (16 rows/WG). Rationale:
//  - publish region per WG = 16 rows x 8B = 128B = exactly 2 cache lines,
//    no line shared between WGs (r15's 12-row/96B straddle poisoned
//    consumer line fetches — the suspected cause of its regression);
//  - straggler max over 48 WGs instead of 96;
//  - single-request sweeps: threads 0..383 poll 2 packs each via ONE
//    global_load_dwordx4 sc0 sc1 (exact 768 cover); threads 384..511
//    (compute waves 6-7) skip polling and arrive at the barrier early —
//    harmless, they never spin during others' compute (r12 lesson was
//    about in-window SPINNING, not early arrival);
//  - device sweep-line rate drops 33% (48 x 96 lines).
// Known risk: 8-wave barrier width.
//
// Encoded lessons: no fences (r3), no RMWs (r7), no extra detect hop (r9),
// no setprio on spinners (r6), no replication (r8), no poll-only spinner
// waves (r6/r12), no non-coherent speculative reads (r14), no dual-stream
// over-polling (r16), publish regions line-aligned (r15), VGPR must fit
// weights (r4/r10), LDS stride 33 (r13).

#define DD 768
#define NSTEPS 8192
#define NWG 48
#define NT 512
#define ROWS_PER_WG 16
#define COLS_PER_LANE 24
#define RING 16
#define LSTRIDE 33
#define LSLOT (COLS_PER_LANE * LSTRIDE)   // 792 words per history slot

#define RING_OFF 0   // RING * DD * 8B packs in d_ws

typedef __attribute__((ext_vector_type(4))) unsigned int u32x4;

__device__ __forceinline__ unsigned long long ld_tag(const unsigned long long* p) {
    return __hip_atomic_load(p, __ATOMIC_RELAXED, __HIP_MEMORY_SCOPE_AGENT);
}

// One coherent 16B load of two (value|tag) packs: x=val0 y=tag0 z=val1 w=tag1.
// sc0 sc1 -> serviced at the device coherence point (validated r12/r13/r15).
__device__ __forceinline__ u32x4 ld_pair(const unsigned long long* p) {
    u32x4 v;
    asm volatile("global_load_dwordx4 %0, %1, off sc0 sc1\n\t"
                 "s_waitcnt vmcnt(0)"
                 : "=v"(v) : "v"(p) : "memory");
    return v;
}

__global__ __launch_bounds__(NT, 1)
void ndde_kernel(const float* __restrict__ x0,
                 const float* __restrict__ tau,
                 const float* __restrict__ Wx,
                 const float* __restrict__ Wy,
                 const float* __restrict__ b,
                 float* __restrict__ out,
                 unsigned long long* __restrict__ ring)
{
    // Padded transposed f32 LDS history (r13): column i at
    // hist[slot*LSLOT + (i%24)*33 + i/24]. Dot-read bank=(k+c)%32 —
    // conflict-free; broadcast writes ~6-way.
    __shared__ float hist[RING * LSLOT];          // 50.7 KB

    const int tid = threadIdx.x;
    const int g   = blockIdx.x;
    const int r   = tid >> 5;            // local row 0..15
    const int c   = tid & 31;            // lane-within-row 0..31
    const int row = g * ROWS_PER_WG + r;
    const int cb  = c * COLS_PER_LANE;

    const float dtf = tau[0] / 10.0f;

    // ---- stage weights as f32 (cvt to f64 at use, exact) ----
    float wxf[COLS_PER_LANE], wyf[COLS_PER_LANE];
    {
        const float* px = Wx + row * DD + cb;
        const float* py = Wy + row * DD + cb;
        #pragma unroll
        for (int i = 0; i < COLS_PER_LANE / 4; ++i) {
            float4 a = *(const float4*)(px + 4 * i);
            wxf[4*i+0] = a.x; wxf[4*i+1] = a.y; wxf[4*i+2] = a.z; wxf[4*i+3] = a.w;
            float4 d2 = *(const float4*)(py + 4 * i);
            wyf[4*i+0] = d2.x; wyf[4*i+1] = d2.y; wyf[4*i+2] = d2.z; wyf[4*i+3] = d2.w;
        }
    }
    #pragma unroll
    for (int i = 0; i < COLS_PER_LANE; ++i) {
        asm volatile("" : "+v"(wxf[i]));
        asm volatile("" : "+v"(wyf[i]));
    }

    const float brow = b[row];
    float xrow = x0[row];                // lane c==0 carries x_j[row]
    if (c == 0) out[row * (NSTEPS + 1) + 0] = xrow;

    for (int j = 0; j < NSTEPS; ++j) {
        // ---- delayed half: y = x_{j-10} from LDS history (frozen math) ----
        double dy0 = 0.0, dy1 = 0.0;
        if (j <= 10) {
            const float* ys = x0 + cb;
            #pragma unroll
            for (int i = 0; i < COLS_PER_LANE / 4; ++i) {
                float4 v = *(const float4*)(ys + 4 * i);
                dy0 = fma((double)wyf[4*i+0], (double)v.x, dy0);
                dy1 = fma((double)wyf[4*i+1], (double)v.y, dy1);
                dy0 = fma((double)wyf[4*i+2], (double)v.z, dy0);
                dy1 = fma((double)wyf[4*i+3], (double)v.w, dy1);
            }
        } else {
            const float* hs = hist + ((j - 10) & (RING - 1)) * LSLOT;
            #pragma unroll
            for (int k = 0; k < COLS_PER_LANE; k += 4) {
                float v0 = hs[(k+0)*LSTRIDE + c];
                float v1 = hs[(k+1)*LSTRIDE + c];
                float v2 = hs[(k+2)*LSTRIDE + c];
                float v3 = hs[(k+3)*LSTRIDE + c];
                dy0 = fma((double)wyf[k+0], (double)v0, dy0);
                dy1 = fma((double)wyf[k+1], (double)v1, dy1);
                dy0 = fma((double)wyf[k+2], (double)v2, dy0);
                dy1 = fma((double)wyf[k+3], (double)v3, dy1);
            }
        }
        double doty = dy0 + dy1;
        #pragma unroll
        for (int off = 1; off < 32; off <<= 1)
            doty += __shfl_xor(doty, off);

        // ---- threads 0..383: 1-request sweep (2 packs each, exact cover),
        // window-confined; broadcast to LDS. Threads 384..511 arrive at the
        // barrier early (no spinning). ----
        if (j >= 1) {
            if (tid < 384) {
                const unsigned tgt = (unsigned)j;
                const unsigned long long* p4 =
                    ring + (j & (RING - 1)) * DD + 2 * tid;
                unsigned v0, v1;
                int tries = 0;
                for (;;) {
                    bool ok;
                    if (tries < 2048) {
                        u32x4 q = ld_pair(p4);
                        v0 = q.x; v1 = q.z;
                        ok = (q.y == tgt) & (q.w == tgt);
                    } else {           // proven fallback (no-hang)
                        unsigned long long q0 = ld_tag(p4 + 0);
                        unsigned long long q1 = ld_tag(p4 + 1);
                        v0 = (unsigned)q0; v1 = (unsigned)q1;
                        ok = ((unsigned)(q0 >> 32) == tgt) &
                             ((unsigned)(q1 >> 32) == tgt);
                    }
                    if (__all(ok)) break;
                    ++tries;
                }
                float* hsw = hist + (j & (RING - 1)) * LSLOT;
                const int iA = 2 * tid, iB = 2 * tid + 1;
                hsw[(iA % 24) * LSTRIDE + (iA / 24)] = __uint_as_float(v0);
                hsw[(iB % 24) * LSTRIDE + (iB / 24)] = __uint_as_float(v1);
            }
            __syncthreads();
        }

        // ---- live half: Wx · x_j from LDS (frozen math) ----
        double dx0 = 0.0, dx1 = 0.0;
        if (j == 0) {
            const float* xs = x0 + cb;
            #pragma unroll
            for (int i = 0; i < COLS_PER_LANE / 4; ++i) {
                float4 v = *(const float4*)(xs + 4 * i);
                dx0 = fma((double)wxf[4*i+0], (double)v.x, dx0);
                dx1 = fma((double)wxf[4*i+1], (double)v.y, dx1);
                dx0 = fma((double)wxf[4*i+2], (double)v.z, dx0);
                dx1 = fma((double)wxf[4*i+3], (double)v.w, dx1);
            }
        } else {
            const float* hs = hist + (j & (RING - 1)) * LSLOT;
            #pragma unroll
            for (int k = 0; k < COLS_PER_LANE; k += 4) {
                float v0 = hs[(k+0)*LSTRIDE + c];
                float v1 = hs[(k+1)*LSTRIDE + c];
                float v2 = hs[(k+2)*LSTRIDE + c];
                float v3 = hs[(k+3)*LSTRIDE + c];
                dx0 = fma((double)wxf[k+0], (double)v0, dx0);
                dx1 = fma((double)wxf[k+1], (double)v1, dx1);
                dx0 = fma((double)wxf[k+2], (double)v2, dx0);
                dx1 = fma((double)wxf[k+3], (double)v3, dx1);
            }
        }
        double dotx = dx0 + dx1;
        #pragma unroll
        for (int off = 1; off < 32; off <<= 1)
            dotx += __shfl_xor(dotx, off);

        if (c == 0) {
            // z = (dot1_f32 + dot2_f32) + b, all fp32 adds (frozen)
            float z = __fadd_rn(__fadd_rn((float)dotx, (float)doty), brow);
            float th;
            float az = fabsf(z);
            if (az < 9.3f) th = (float)tanh((double)z);  // correctly-rounded
            else           th = (z > 0.0f) ? 1.0f : -1.0f;
            // x_next = x + dt*F, fp32 mul then fp32 add (frozen)
            xrow = __fadd_rn(xrow, __fmul_rn(dtf, th));

            // publish: (value|tag) in one relaxed agent-scope 8B store
            unsigned long long pack =
                ((unsigned long long)(unsigned)(j + 1) << 32) |
                (unsigned long long)__float_as_uint(xrow);
            __hip_atomic_store(&ring[((j + 1) & (RING - 1)) * DD + row], pack,
                               __ATOMIC_RELAXED, __HIP_MEMORY_SCOPE_AGENT);

            // trajectory write — off the critical path
            out[row * (NSTEPS + 1) + (j + 1)] = xrow;
        }
    }
}

extern "C" void kernel_launch(void* const* d_in, const int* in_sizes, int n_in,
                              void* d_out, int out_size, void* d_ws, size_t ws_size,
                              hipStream_t stream) {
    (void)in_sizes; (void)n_in; (void)out_size; (void)ws_size;

    const float* x0  = (const float*)d_in[0];
    const float* tau = (const float*)d_in[1];
    const float* Wx  = (const float*)d_in[2];
    const float* Wy  = (const float*)d_in[3];
    const float* b   = (const float*)d_in[4];
    float* out = (float*)d_out;

    unsigned long long* ring = (unsigned long long*)((char*)d_ws + RING_OFF);

    // No memset needed: strict tag==j matching rejects 0xAA poison and stale
    // replay tags (slot j%16 is freshly rewritten long before step j needs it).
    ndde_kernel<<<NWG, NT, 0, stream>>>(x0, tau, Wx, Wy, b, out, ring);
}

// Round 18
// 13786.383 us; speedup vs baseline: 1.2215x; 1.1874x over previous
//
#include <hip/hip_runtime.h>
#include <math.h>

// NDDE forward-Euler DDE solve, D=768, N=8192 steps.
// x_{j+1} = x_j + dt * tanh(Wx x_j + Wy x_{j-10} + b),  dt = tau/10.
// Output: trajectory [D][N+1] fp32, out[i*(N+1)+k] = x_k[i].
//
// NUMERICS ARE FROZEN (passes at absmax 16.0 / thr 16.4): fp64-exact dots
// rounded per-dot to fp32; fp32 adds for z; correctly-rounded fp32 tanh via
// fp64; fp32 state update mul-then-add; per-row 32-lane x 24-col ownership,
// FMA order and shuffle reduction tree IDENTICAL to rounds 5/11/13.
//
// Round 18 = r13 (best, 14.25 ms) + ONE change: s_sleep 5 (~320 cy) before
// the FIRST sweep of each step. Cycle model: first sweep previously issued
// ~1250 cy after barrier, racing the slowest publish-visible (~1150-1400).
// A 150-cy-early sample misses, retries +1 sweep period, publishes late,
// and pushes other WGs into the same miss next step ("miss-the-bus" limp
// mode — explains measured 4170 cy/step vs ~2200 intrinsic). Delaying the
// first sample past the slowest publisher guarantees first-sweep hits AND
// removes failed-sweep MALL traffic from the publish window (the r12/r16
// toxicity) at zero cost.
//
// Encoded lessons: no fences (r3), no RMWs (r7), no extra detect hop (r9),
// no setprio on spinners (r6), no replication (r8), no poll-only spinner
// waves (r6/r12), no non-coherent speculative reads (r14), no dual-stream
// over-polling (r16), 96x256 beats all other topologies (r10/r15/r17),
// VGPR must fit weights (r4/r10), LDS stride 33 (r13).

#define DD 768
#define NSTEPS 8192
#define NWG 96
#define NT 256
#define ROWS_PER_WG 8
#define COLS_PER_LANE 24
#define RING 16
#define LSTRIDE 33
#define LSLOT (COLS_PER_LANE * LSTRIDE)   // 792 words per history slot

#define RING_OFF 0   // RING * DD * 8B packs in d_ws

typedef __attribute__((ext_vector_type(4))) unsigned int u32x4;
typedef __attribute__((ext_vector_type(2))) unsigned int u32x2;

__device__ __forceinline__ unsigned long long ld_tag(const unsigned long long* p) {
    return __hip_atomic_load(p, __ATOMIC_RELAXED, __HIP_MEMORY_SCOPE_AGENT);
}

// One sweep: both poll loads in flight, single wait. sc0 sc1 -> coherent
// read at the device coherence point (validated r12/r13).
__device__ __forceinline__ void sweep_ld(const unsigned long long* p4,
                                         const unsigned long long* p2,
                                         u32x4* q, u32x2* r2) {
    asm volatile("global_load_dwordx4 %0, %2, off sc0 sc1\n\t"
                 "global_load_dwordx2 %1, %3, off sc0 sc1\n\t"
                 "s_waitcnt vmcnt(0)"
                 : "=&v"(*q), "=&v"(*r2)
                 : "v"(p4), "v"(p2)
                 : "memory");
}

__global__ __launch_bounds__(NT, 1)
void ndde_kernel(const float* __restrict__ x0,
                 const float* __restrict__ tau,
                 const float* __restrict__ Wx,
                 const float* __restrict__ Wy,
                 const float* __restrict__ b,
                 float* __restrict__ out,
                 unsigned long long* __restrict__ ring)
{
    // Padded transposed f32 LDS history (r13): column i at
    // hist[slot*LSLOT + (i%24)*33 + i/24]. Dot-read bank=(k+c)%32 —
    // conflict-free; broadcast writes ~6-way.
    __shared__ float hist[RING * LSLOT];          // 50.7 KB

    const int tid = threadIdx.x;
    const int g   = blockIdx.x;
    const int r   = tid >> 5;            // local row 0..7
    const int c   = tid & 31;            // lane-within-row 0..31
    const int row = g * ROWS_PER_WG + r;
    const int cb  = c * COLS_PER_LANE;

    const float dtf = tau[0] / 10.0f;

    // ---- stage weights as f32 (cvt to f64 at use, exact) ----
    float wxf[COLS_PER_LANE], wyf[COLS_PER_LANE];
    {
        const float* px = Wx + row * DD + cb;
        const float* py = Wy + row * DD + cb;
        #pragma unroll
        for (int i = 0; i < COLS_PER_LANE / 4; ++i) {
            float4 a = *(const float4*)(px + 4 * i);
            wxf[4*i+0] = a.x; wxf[4*i+1] = a.y; wxf[4*i+2] = a.z; wxf[4*i+3] = a.w;
            float4 d2 = *(const float4*)(py + 4 * i);
            wyf[4*i+0] = d2.x; wyf[4*i+1] = d2.y; wyf[4*i+2] = d2.z; wyf[4*i+3] = d2.w;
        }
    }
    #pragma unroll
    for (int i = 0; i < COLS_PER_LANE; ++i) {
        asm volatile("" : "+v"(wxf[i]));
        asm volatile("" : "+v"(wyf[i]));
    }

    const float brow = b[row];
    float xrow = x0[row];                // lane c==0 carries x_j[row]
    if (c == 0) out[row * (NSTEPS + 1) + 0] = xrow;

    for (int j = 0; j < NSTEPS; ++j) {
        // ---- delayed half: y = x_{j-10} from LDS history (frozen math) ----
        double dy0 = 0.0, dy1 = 0.0;
        if (j <= 10) {
            const float* ys = x0 + cb;
            #pragma unroll
            for (int i = 0; i < COLS_PER_LANE / 4; ++i) {
                float4 v = *(const float4*)(ys + 4 * i);
                dy0 = fma((double)wyf[4*i+0], (double)v.x, dy0);
                dy1 = fma((double)wyf[4*i+1], (double)v.y, dy1);
                dy0 = fma((double)wyf[4*i+2], (double)v.z, dy0);
                dy1 = fma((double)wyf[4*i+3], (double)v.w, dy1);
            }
        } else {
            const float* hs = hist + ((j - 10) & (RING - 1)) * LSLOT;
            #pragma unroll
            for (int k = 0; k < COLS_PER_LANE; k += 4) {
                float v0 = hs[(k+0)*LSTRIDE + c];
                float v1 = hs[(k+1)*LSTRIDE + c];
                float v2 = hs[(k+2)*LSTRIDE + c];
                float v3 = hs[(k+3)*LSTRIDE + c];
                dy0 = fma((double)wyf[k+0], (double)v0, dy0);
                dy1 = fma((double)wyf[k+1], (double)v1, dy1);
                dy0 = fma((double)wyf[k+2], (double)v2, dy0);
                dy1 = fma((double)wyf[k+3], (double)v3, dy1);
            }
        }
        double doty = dy0 + dy1;
        #pragma unroll
        for (int off = 1; off < 32; off <<= 1)
            doty += __shfl_xor(doty, off);

        // ---- ALL 4 waves: delay-aligned first sweep, then 1-RT sweeps of
        // 3 packs/thread (2 requests, one wait), broadcast to LDS ----
        if (j >= 1) {
            const unsigned tgt = (unsigned)j;
            const unsigned long long* base = ring + (j & (RING - 1)) * DD;
            const unsigned long long* p4 = base + 2 * tid;      // packs 2t,2t+1
            const unsigned long long* p2 = base + 512 + tid;    // pack 512+t
            unsigned v0, v1, v2;

            // align first sample past the slowest publish-visible time;
            // also keeps poll traffic out of the publish window (r12/r16)
            asm volatile("s_sleep 5");

            int tries = 0;
            for (;;) {
                bool ok;
                if (tries < 2048) {
                    u32x4 q; u32x2 s;
                    sweep_ld(p4, p2, &q, &s);
                    v0 = q.x; v1 = q.z; v2 = s.x;
                    ok = (q.y == tgt) & (q.w == tgt) & (s.y == tgt);
                } else {               // r11-proven fallback (no-hang)
                    unsigned long long q0 = ld_tag(p4 + 0);
                    unsigned long long q1 = ld_tag(p4 + 1);
                    unsigned long long q2 = ld_tag(p2);
                    v0 = (unsigned)q0; v1 = (unsigned)q1; v2 = (unsigned)q2;
                    ok = ((unsigned)(q0 >> 32) == tgt) &
                         ((unsigned)(q1 >> 32) == tgt) &
                         ((unsigned)(q2 >> 32) == tgt);
                }
                if (__all(ok)) break;
                ++tries;
            }
            float* hsw = hist + (j & (RING - 1)) * LSLOT;
            const int iA = 2 * tid, iB = 2 * tid + 1, iC = 512 + tid;
            hsw[(iA % 24) * LSTRIDE + (iA / 24)] = __uint_as_float(v0);
            hsw[(iB % 24) * LSTRIDE + (iB / 24)] = __uint_as_float(v1);
            hsw[(iC % 24) * LSTRIDE + (iC / 24)] = __uint_as_float(v2);
            __syncthreads();
        }

        // ---- live half: Wx · x_j from LDS (frozen math) ----
        double dx0 = 0.0, dx1 = 0.0;
        if (j == 0) {
            const float* xs = x0 + cb;
            #pragma unroll
            for (int i = 0; i < COLS_PER_LANE / 4; ++i) {
                float4 v = *(const float4*)(xs + 4 * i);
                dx0 = fma((double)wxf[4*i+0], (double)v.x, dx0);
                dx1 = fma((double)wxf[4*i+1], (double)v.y, dx1);
                dx0 = fma((double)wxf[4*i+2], (double)v.z, dx0);
                dx1 = fma((double)wxf[4*i+3], (double)v.w, dx1);
            }
        } else {
            const float* hs = hist + (j & (RING - 1)) * LSLOT;
            #pragma unroll
            for (int k = 0; k < COLS_PER_LANE; k += 4) {
                float v0 = hs[(k+0)*LSTRIDE + c];
                float v1 = hs[(k+1)*LSTRIDE + c];
                float v2 = hs[(k+2)*LSTRIDE + c];
                float v3 = hs[(k+3)*LSTRIDE + c];
                dx0 = fma((double)wxf[k+0], (double)v0, dx0);
                dx1 = fma((double)wxf[k+1], (double)v1, dx1);
                dx0 = fma((double)wxf[k+2], (double)v2, dx0);
                dx1 = fma((double)wxf[k+3], (double)v3, dx1);
            }
        }
        double dotx = dx0 + dx1;
        #pragma unroll
        for (int off = 1; off < 32; off <<= 1)
            dotx += __shfl_xor(dotx, off);

        if (c == 0) {
            // z = (dot1_f32 + dot2_f32) + b, all fp32 adds (frozen)
            float z = __fadd_rn(__fadd_rn((float)dotx, (float)doty), brow);
            float th;
            float az = fabsf(z);
            if (az < 9.3f) th = (float)tanh((double)z);  // correctly-rounded
            else           th = (z > 0.0f) ? 1.0f : -1.0f;
            // x_next = x + dt*F, fp32 mul then fp32 add (frozen)
            xrow = __fadd_rn(xrow, __fmul_rn(dtf, th));

            // publish: (value|tag) in one relaxed agent-scope 8B store
            unsigned long long pack =
                ((unsigned long long)(unsigned)(j + 1) << 32) |
                (unsigned long long)__float_as_uint(xrow);
            __hip_atomic_store(&ring[((j + 1) & (RING - 1)) * DD + row], pack,
                               __ATOMIC_RELAXED, __HIP_MEMORY_SCOPE_AGENT);

            // trajectory write — off the critical path
            out[row * (NSTEPS + 1) + (j + 1)] = xrow;
        }
    }
}

extern "C" void kernel_launch(void* const* d_in, const int* in_sizes, int n_in,
                              void* d_out, int out_size, void* d_ws, size_t ws_size,
                              hipStream_t stream) {
    (void)in_sizes; (void)n_in; (void)out_size; (void)ws_size;

    const float* x0  = (const float*)d_in[0];
    const float* tau = (const float*)d_in[1];
    const float* Wx  = (const float*)d_in[2];
    const float* Wy  = (const float*)d_in[3];
    const float* b   = (const float*)d_in[4];
    float* out = (float*)d_out;

    unsigned long long* ring = (unsigned long long*)((char*)d_ws + RING_OFF);

    // No memset needed: strict tag==j matching rejects 0xAA poison and stale
    // replay tags (slot j%16 is freshly rewritten long before step j needs it).
    ndde_kernel<<<NWG, NT, 0, stream>>>(x0, tau, Wx, Wy, b, out, ring);
}